// Round 17
// baseline (296.113 us; speedup 1.0000x reference)
//
#include <hip/hip_runtime.h>

typedef unsigned short USHORT;
typedef __attribute__((ext_vector_type(8))) short short8;
typedef __attribute__((ext_vector_type(4))) float f32x4;

#define NB   16
#define NC   512
#define NHW  4096
#define NT   77
#define NF   768
#define NHEAD 8
#define NDH  64
#define TPAD 80
#define TPAD2 96
#define PSTR 104   // P-tile LDS row stride in shorts: 208B == 20 mod 32 banks
#define BKS  64

__device__ __forceinline__ USHORT f2bf(float f){
  unsigned u = __builtin_bit_cast(unsigned, f);
  u += 0x7fffu + ((u >> 16) & 1u);
  return (USHORT)(u >> 16);
}
__device__ __forceinline__ unsigned pack2(float a, float b){
  return (unsigned)f2bf(a) | ((unsigned)f2bf(b) << 16);
}

__device__ __forceinline__ void gload16(const void* g, void* l){
  __builtin_amdgcn_global_load_lds((const __attribute__((address_space(1))) unsigned*)g,
                                   (__attribute__((address_space(3))) unsigned*)l, 16, 0, 0);
}

// XCD-aware swizzle of a 32-wide tile index (T1).
__device__ __forceinline__ int xcd_swz32(int x){ return ((x & 7) << 2) | (x >> 3); }

// ---------------- single-launch f32 -> bf16 convert of all 5 arrays ----------------
__global__ __launch_bounds__(256) void cvt_all_kernel(const float* __restrict__ s0, USHORT* __restrict__ d0, int n0,
                                                      const float* __restrict__ s1, USHORT* __restrict__ d1, int n1,
                                                      const float* __restrict__ s2, USHORT* __restrict__ d2, int n2,
                                                      const float* __restrict__ s3, USHORT* __restrict__ d3, int n3,
                                                      const float* __restrict__ s4, USHORT* __restrict__ d4, int n4){
  int i = blockIdx.x * 256 + threadIdx.x;
  const float* s; USHORT* d;
  if (i < n0){ s = s0; d = d0; }
  else { i -= n0;
    if (i < n1){ s = s1; d = d1; }
    else { i -= n1;
      if (i < n2){ s = s2; d = d2; }
      else { i -= n2;
        if (i < n3){ s = s3; d = d3; }
        else { i -= n3;
          if (i >= n4) return;
          s = s4; d = d4; } } } }
  float4 v = ((const float4*)s)[i];
  uint2 pk; pk.x = pack2(v.x, v.y); pk.y = pack2(v.z, v.w);
  ((uint2*)d)[i] = pk;
}

// ---------------- GroupNorm stats: one block per (b,group), contiguous 256KB reads ----------------
__global__ __launch_bounds__(256) void gnstats_kernel(const float* __restrict__ x, float2* __restrict__ stats){
  int gid = blockIdx.x;
  const float4* p = (const float4*)(x + (size_t)gid * 65536);
  float s = 0.f, s2 = 0.f;
  for (int i = threadIdx.x; i < 16384; i += 256){
    float4 v = p[i];
    s  += v.x + v.y + v.z + v.w;
    s2 += v.x*v.x + v.y*v.y + v.z*v.z + v.w*v.w;
  }
  #pragma unroll
  for (int off = 32; off; off >>= 1){ s += __shfl_down(s, off); s2 += __shfl_down(s2, off); }
  __shared__ float red[8];
  int wv = threadIdx.x >> 6;
  if ((threadIdx.x & 63) == 0){ red[wv] = s; red[4 + wv] = s2; }
  __syncthreads();
  if (threadIdx.x == 0){
    float S  = red[0] + red[1] + red[2] + red[3];
    float S2 = red[4] + red[5] + red[6] + red[7];
    float mu = S * (1.0f / 65536.0f);
    float var = S2 * (1.0f / 65536.0f) - mu * mu;
    stats[gid] = make_float2(mu, 1.0f / sqrtf(var + 1e-5f));
  }
}

// ---------------- normalize + transpose with COALESCED writes ----------------
// One block per (b,g) (XCD-paired so g,g+1 land on the same XCD and their 32B write halves
// merge into 64B lines). 1024 threads x 4 spatial. Channels processed 8 at a time in a
// NON-unrolled loop -> ~35 live VGPRs (R15 lesson: __launch_bounds__(1024) gives a 64-reg
// budget; 16-ch-at-once variants all spilled). Old gnorm_tr wrote scalar 2B @1KB stride
// (64x amplification) - this writes 16B packed segments.
__global__ __launch_bounds__(1024) void gn_tr_kernel(const float* __restrict__ x,
                                                     const float2* __restrict__ stats,
                                                     const float* __restrict__ gamma,
                                                     const float* __restrict__ beta,
                                                     USHORT* __restrict__ xnT){
  const int dsp = blockIdx.x;
  const int o = (dsp >> 3) & 1;
  const int p = (dsp >> 4) * 8 + (dsp & 7);
  const int base = 2 * p + o;               // b*32 + g
  const int b = base >> 5, g = base & 31;
  const int t = threadIdx.x;                // owns s = t*4 .. t*4+3

  const float2 st = stats[b * 32 + g];
  const float mu = st.x, rs = st.y;
  const float* xg = x + ((size_t)b * NC + g * 16) * NHW + t * 4;
  USHORT* ob = xnT + ((size_t)b * NHW + t * 4) * NC + g * 16;

  for (int half = 0; half < 2; ++half){     // NOT unrolled: keeps live set ~35 regs
    const int cb = g * 16 + half * 8;
    const float g0 = gamma[cb+0]*rs, g1 = gamma[cb+1]*rs, g2 = gamma[cb+2]*rs, g3 = gamma[cb+3]*rs;
    const float g4 = gamma[cb+4]*rs, g5 = gamma[cb+5]*rs, g6 = gamma[cb+6]*rs, g7 = gamma[cb+7]*rs;
    const float b0 = beta[cb+0], b1 = beta[cb+1], b2 = beta[cb+2], b3 = beta[cb+3];
    const float b4 = beta[cb+4], b5 = beta[cb+5], b6 = beta[cb+6], b7 = beta[cb+7];
    const float* xh = xg + (size_t)(half * 8) * NHW;
    float4 v0 = *(const float4*)(xh + 0 * (size_t)NHW);
    float4 v1 = *(const float4*)(xh + 1 * (size_t)NHW);
    float4 v2 = *(const float4*)(xh + 2 * (size_t)NHW);
    float4 v3 = *(const float4*)(xh + 3 * (size_t)NHW);
    float4 v4 = *(const float4*)(xh + 4 * (size_t)NHW);
    float4 v5 = *(const float4*)(xh + 5 * (size_t)NHW);
    float4 v6 = *(const float4*)(xh + 6 * (size_t)NHW);
    float4 v7 = *(const float4*)(xh + 7 * (size_t)NHW);
    USHORT* oh = ob + half * 8;
#define GN_EMIT(COMP, EIDX) { \
    unsigned w0 = pack2((v0.COMP - mu) * g0 + b0, (v1.COMP - mu) * g1 + b1); \
    unsigned w1 = pack2((v2.COMP - mu) * g2 + b2, (v3.COMP - mu) * g3 + b3); \
    unsigned w2 = pack2((v4.COMP - mu) * g4 + b4, (v5.COMP - mu) * g5 + b5); \
    unsigned w3 = pack2((v6.COMP - mu) * g6 + b6, (v7.COMP - mu) * g7 + b7); \
    uint4 pk{w0, w1, w2, w3};                                                \
    *(uint4*)(oh + (size_t)(EIDX) * NC) = pk; }
    GN_EMIT(x, 0) GN_EMIT(y, 1) GN_EMIT(z, 2) GN_EMIT(w, 3)
#undef GN_EMIT
  }
}

// ---------------- 128x128-tile single-buffer LDS GEMM core (R2/R6 proven) ----------------
// Frozen: min-waves>=4 (R5/R7), dbuf (R3), 256^2-2phase (R9), LDS-transpose epilogue (R10)
// all measured null/regressions vs this structure.
__device__ __forceinline__ void gemm128_core(const USHORT* __restrict__ A, const USHORT* __restrict__ B,
                                             int m0, size_t brow0, USHORT* Alds, USHORT* Blds,
                                             f32x4 (&acc)[4][4]){
  const int tid = threadIdx.x;
  const int lane = tid & 63, wave = tid >> 6;
  const int l15 = lane & 15, lg = lane >> 4;
  const int wm = wave >> 1, wn = wave & 1;
  const int srow = lane >> 3, sslot = lane & 7;

  #pragma unroll
  for (int i = 0; i < 4; i++)
    #pragma unroll
    for (int j = 0; j < 4; j++) acc[i][j] = f32x4{0.f, 0.f, 0.f, 0.f};

  for (int k0 = 0; k0 < 512; k0 += BKS){
    #pragma unroll
    for (int i = 0; i < 4; i++){
      const int r0 = wave * 32 + i * 8;
      const int row = r0 + srow;
      const int slot = sslot ^ (row & 7);
      gload16(A + (size_t)(m0 + row) * NC + k0 + slot * 8, Alds + r0 * BKS);
      gload16(B + brow0 + (size_t)row * NC + k0 + slot * 8, Blds + r0 * BKS);
    }
    __syncthreads();
    #pragma unroll
    for (int ks = 0; ks < 2; ks++){
      short8 af[4], bf[4];
      #pragma unroll
      for (int i = 0; i < 4; i++){
        const int row = wm * 64 + i * 16 + l15;
        af[i] = *(const short8*)(Alds + row * BKS + (((ks * 4 + lg) ^ (row & 7)) * 8));
      }
      #pragma unroll
      for (int j = 0; j < 4; j++){
        const int row = wn * 64 + j * 16 + l15;
        bf[j] = *(const short8*)(Blds + row * BKS + (((ks * 4 + lg) ^ (row & 7)) * 8));
      }
      #pragma unroll
      for (int i = 0; i < 4; i++)
        #pragma unroll
        for (int j = 0; j < 4; j++)
          acc[i][j] = __builtin_amdgcn_mfma_f32_16x16x32_bf16(af[i], bf[j], acc[i][j], 0, 0, 0);
    }
    __syncthreads();
  }
}

// ---------------- FUSED Q-GEMM + attention (R8 proven, unchanged) ----------------
__global__ __launch_bounds__(256, 3) void qattn_kernel(const USHORT* __restrict__ Aw, const USHORT* __restrict__ Bx,
                                                       const float* __restrict__ bias,
                                                       const USHORT* __restrict__ kb, const USHORT* __restrict__ vb,
                                                       USHORT* __restrict__ attnT){
  __shared__ USHORT smem[26624];   // 52 KB
  const int lane = threadIdx.x & 63, wave = threadIdx.x >> 6;
  const int l15 = lane & 15, lg = lane >> 4;
  const int b = blockIdx.z;
  const int xx = xcd_swz32(blockIdx.x);
  const int m0b = blockIdx.y * 128;
  const size_t brow0 = ((size_t)b * NHW + xx * 128) * NC;
  f32x4 acc[4][4];
  gemm128_core(Aw, Bx, m0b, brow0, smem, smem + 8192, acc);

  const int wm = wave >> 1, wn = wave & 1;
  const int h = blockIdx.y * 2 + wm;
  const int m0 = h * 64;
  const int s0 = xx * 128 + wn * 64;
  const size_t bh = (size_t)b * NHEAD + h;
  char* qt = (char*)(smem + wave * 6656);     // 13 KB wave-private region

  #pragma unroll
  for (int i = 0; i < 4; i++){
    const int dbase = i * 16 + lg * 4;
    float b0 = bias[m0 + dbase], b1 = bias[m0 + dbase + 1];
    float b2 = bias[m0 + dbase + 2], b3 = bias[m0 + dbase + 3];
    #pragma unroll
    for (int j = 0; j < 4; j++){
      const int s = j * 16 + l15;
      uint2 pk;
      pk.x = pack2(acc[i][j][0] + b0, acc[i][j][1] + b1);
      pk.y = pack2(acc[i][j][2] + b2, acc[i][j][3] + b3);
      *(uint2*)(qt + s * 128 + ((dbase * 2) ^ ((s & 7) << 4))) = pk;
    }
  }
  short8 aq[4][2];
  #pragma unroll
  for (int i = 0; i < 4; i++){
    const int s = i * 16 + l15;
    #pragma unroll
    for (int ks = 0; ks < 2; ks++)
      aq[i][ks] = *(const short8*)(qt + s * 128 + ((ks * 64 + lg * 16) ^ ((s & 7) << 4)));
  }

  USHORT* plds = (USHORT*)qt;
  uint4 z{0u, 0u, 0u, 0u};
  *(uint4*)(qt + lane * (PSTR * 2) + 160) = z;
  *(uint4*)(qt + lane * (PSTR * 2) + 176) = z;

  short8 bk[5][2];
  const USHORT* kp = kb + bh * TPAD * NDH;
  #pragma unroll
  for (int j = 0; j < 5; j++)
    #pragma unroll
    for (int ks = 0; ks < 2; ks++)
      bk[j][ks] = *(const short8*)(kp + (j * 16 + l15) * NDH + ks * 32 + lg * 8);

  f32x4 sacc[4][5];
  #pragma unroll
  for (int i = 0; i < 4; i++)
    #pragma unroll
    for (int j = 0; j < 5; j++) sacc[i][j] = f32x4{0.f, 0.f, 0.f, 0.f};
  #pragma unroll
  for (int ks = 0; ks < 2; ks++)
    #pragma unroll
    for (int i = 0; i < 4; i++)
      #pragma unroll
      for (int j = 0; j < 5; j++)
        sacc[i][j] = __builtin_amdgcn_mfma_f32_16x16x32_bf16(aq[i][ks], bk[j][ks], sacc[i][j], 0, 0, 0);

  const float scale = 0.125f;
  #pragma unroll
  for (int i = 0; i < 4; i++){
    float v[5][4], mx[4], sm[4];
    #pragma unroll
    for (int r = 0; r < 4; r++) mx[r] = -3.0e38f;
    #pragma unroll
    for (int j = 0; j < 5; j++)
      #pragma unroll
      for (int r = 0; r < 4; r++){
        float t = sacc[i][j][r] * scale;
        if (j == 4 && l15 >= 13) t = -3.0e38f;
        v[j][r] = t;
        mx[r] = fmaxf(mx[r], t);
      }
    #pragma unroll
    for (int r = 0; r < 4; r++)
      #pragma unroll
      for (int d = 1; d < 16; d <<= 1) mx[r] = fmaxf(mx[r], __shfl_xor(mx[r], d));
    #pragma unroll
    for (int r = 0; r < 4; r++) sm[r] = 0.f;
    #pragma unroll
    for (int j = 0; j < 5; j++)
      #pragma unroll
      for (int r = 0; r < 4; r++){
        float p = __expf(v[j][r] - mx[r]);
        v[j][r] = p;
        sm[r] += p;
      }
    #pragma unroll
    for (int r = 0; r < 4; r++)
      #pragma unroll
      for (int d = 1; d < 16; d <<= 1) sm[r] += __shfl_xor(sm[r], d);
    #pragma unroll
    for (int r = 0; r < 4; r++){
      float inv = 1.0f / sm[r];
      #pragma unroll
      for (int j = 0; j < 5; j++)
        plds[(i * 16 + lg * 4 + r) * PSTR + j * 16 + l15] = f2bf(v[j][r] * inv);
    }
  }

  f32x4 oacc[4][4];
  #pragma unroll
  for (int it = 0; it < 4; it++)
    #pragma unroll
    for (int jt = 0; jt < 4; jt++) oacc[it][jt] = f32x4{0.f, 0.f, 0.f, 0.f};
  const USHORT* vp = vb + bh * NDH * TPAD2;
  #pragma unroll
  for (int ks = 0; ks < 3; ks++){
    short8 av[4], bpv[4];
    #pragma unroll
    for (int it = 0; it < 4; it++)
      av[it] = *(const short8*)(vp + (it * 16 + l15) * TPAD2 + ks * 32 + lg * 8);
    #pragma unroll
    for (int jt = 0; jt < 4; jt++)
      bpv[jt] = *(const short8*)(plds + (jt * 16 + l15) * PSTR + ks * 32 + lg * 8);
    #pragma unroll
    for (int it = 0; it < 4; it++)
      #pragma unroll
      for (int jt = 0; jt < 4; jt++)
        oacc[it][jt] = __builtin_amdgcn_mfma_f32_16x16x32_bf16(av[it], bpv[jt], oacc[it][jt], 0, 0, 0);
  }

  USHORT* ob = attnT + ((size_t)b * NHW + s0) * NC + h * NDH;
  #pragma unroll
  for (int it = 0; it < 4; it++)
    #pragma unroll
    for (int jt = 0; jt < 4; jt++){
      const int sl = jt * 16 + l15;
      uint2 pk;
      pk.x = pack2(oacc[it][jt][0], oacc[it][jt][1]);
      pk.y = pack2(oacc[it][jt][2], oacc[it][jt][3]);
      *(uint2*)(ob + (size_t)sl * NC + it * 16 + lg * 4) = pk;
    }
}

// ---------------- proj GEMM + bias + residual -> out fp32 [b][c][hw] (R6/R8 proven) ----------------
__global__ __launch_bounds__(256, 3) void projgemm_kernel(const USHORT* __restrict__ Aw, const USHORT* __restrict__ Battn,
                                                          const float* __restrict__ bias, const float* __restrict__ xres,
                                                          float* __restrict__ out){
  __shared__ USHORT Alds[128 * BKS], Blds[128 * BKS];
  const int b = blockIdx.z;
  const int xx = xcd_swz32(blockIdx.x);
  const int m0b = blockIdx.y * 128;
  const size_t brow0 = ((size_t)b * NHW + xx * 128) * NC;
  f32x4 acc[4][4];
  gemm128_core(Aw, Battn, m0b, brow0, Alds, Blds, acc);

  const int lane = threadIdx.x & 63, wave = threadIdx.x >> 6;
  const int l15 = lane & 15, lg = lane >> 4;
  const int m0 = m0b + (wave >> 1) * 64;
  const int n0 = xx * 128 + (wave & 1) * 64;
  #pragma unroll
  for (int i = 0; i < 4; i++){
    const int ob = m0 + i * 16 + lg * 4;
    #pragma unroll
    for (int r = 0; r < 4; r++){
      const int oc = ob + r;
      const float bb = bias[oc];
      #pragma unroll
      for (int j = 0; j < 4; j++){
        const int s = n0 + j * 16 + l15;
        const size_t idx = ((size_t)b * NC + oc) * NHW + s;
        out[idx] = acc[i][j][r] + bb + xres[idx];
      }
    }
  }
}

// ---------------- small-K MFMA core for the 77-token projections ----------------
template<int KLEN>
__device__ __forceinline__ void mfma_core(const USHORT* const (&ap)[4], const USHORT* const (&bp)[4],
                                          f32x4 (&acc)[4][4]){
  short8 a_c[4], b_c[4];
  #pragma unroll
  for (int i = 0; i < 4; i++){ a_c[i] = *(const short8*)ap[i]; b_c[i] = *(const short8*)bp[i]; }
  #pragma unroll 2
  for (int k0 = 0; k0 < KLEN; k0 += 32){
    short8 a_n[4], b_n[4];
    if (k0 + 32 < KLEN){
      #pragma unroll
      for (int i = 0; i < 4; i++){
        a_n[i] = *(const short8*)(ap[i] + k0 + 32);
        b_n[i] = *(const short8*)(bp[i] + k0 + 32);
      }
    }
    #pragma unroll
    for (int i = 0; i < 4; i++)
      #pragma unroll
      for (int j = 0; j < 4; j++)
        acc[i][j] = __builtin_amdgcn_mfma_f32_16x16x32_bf16(a_c[i], b_c[j], acc[i][j], 0, 0, 0);
    #pragma unroll
    for (int i = 0; i < 4; i++){ a_c[i] = a_n[i]; b_c[i] = b_n[i]; }
  }
}

// ---------------- K+V GEMM (single launch, mode = blockIdx.y) + raw-reshape scatter ----------------
__global__ __launch_bounds__(256, 2) void kvgemm_kernel(const USHORT* __restrict__ kw, const USHORT* __restrict__ vw,
                                                        const USHORT* __restrict__ Tx,
                                                        const float* __restrict__ kbias, const float* __restrict__ vbias,
                                                        USHORT* __restrict__ kdst, USHORT* __restrict__ vdst){
  const int lane = threadIdx.x & 63, wave = threadIdx.x >> 6;
  const int l15 = lane & 15, lg = lane >> 4;
  const int b = blockIdx.z;
  const int mode = blockIdx.y;
  const USHORT* Wt = mode ? vw : kw;
  const float* bias = mode ? vbias : kbias;
  USHORT* dst = mode ? vdst : kdst;
  const int m0 = (wave >> 1) * 64;
  const int n0 = blockIdx.x * 128 + (wave & 1) * 64;
  const USHORT* ap[4]; const USHORT* bp[4];
  #pragma unroll
  for (int i = 0; i < 4; i++){
    int r = m0 + i * 16 + l15; r = r > 76 ? 76 : r;
    ap[i] = Tx + ((size_t)b * NT + r) * NF + lg * 8;
  }
  #pragma unroll
  for (int i = 0; i < 4; i++) bp[i] = Wt + (size_t)(n0 + i * 16 + l15) * NF + lg * 8;
  f32x4 acc[4][4];
  #pragma unroll
  for (int i = 0; i < 4; i++)
    #pragma unroll
    for (int j = 0; j < 4; j++) acc[i][j] = f32x4{0.f, 0.f, 0.f, 0.f};
  mfma_core<NF>(ap, bp, acc);
  #pragma unroll
  for (int i = 0; i < 4; i++){
    const int tb = m0 + i * 16 + lg * 4;
    #pragma unroll
    for (int r = 0; r < 4; r++){
      const int t = tb + r;
      if (t < NT){
        #pragma unroll
        for (int j = 0; j < 4; j++){
          const int c = n0 + j * 16 + l15;
          float v = acc[i][j][r] + bias[c];
          int fi = t * NC + c;
          int hh = fi / 4928;
          int rem = fi - hh * 4928;
          int dd = rem / 77;
          int tt = rem - dd * 77;
          size_t bhh = (size_t)(b * NHEAD + hh);
          if (mode == 0) dst[(bhh * TPAD + tt) * NDH + dd] = f2bf(v);
          else           dst[(bhh * NDH + dd) * TPAD2 + tt] = f2bf(v);
        }
      }
    }
  }
}

extern "C" void kernel_launch(void* const* d_in, const int* in_sizes, int n_in,
                              void* d_out, int out_size, void* d_ws, size_t ws_size,
                              hipStream_t stream){
  const float* x    = (const float*)d_in[0];
  const float* text = (const float*)d_in[1];
  const float* gn_g = (const float*)d_in[2];
  const float* gn_b = (const float*)d_in[3];
  const float* q_w  = (const float*)d_in[4];
  const float* q_b  = (const float*)d_in[5];
  const float* k_w  = (const float*)d_in[6];
  const float* k_b  = (const float*)d_in[7];
  const float* v_w  = (const float*)d_in[8];
  const float* v_b  = (const float*)d_in[9];
  const float* p_w  = (const float*)d_in[10];
  const float* p_b  = (const float*)d_in[11];
  float* out = (float*)d_out;

  char* ws = (char*)d_ws;
  size_t off = 0;
  auto alloc = [&](size_t bytes){ size_t o = off; off = (off + bytes + 255) & ~(size_t)255; return o; };
  size_t o_stats = alloc(512 * 8);
  size_t o_qwb   = alloc((size_t)NC * NC * 2);
  size_t o_pwb   = alloc((size_t)NC * NC * 2);
  size_t o_kwb   = alloc((size_t)NC * NF * 2);
  size_t o_vwb   = alloc((size_t)NC * NF * 2);
  size_t o_txb   = alloc((size_t)NB * NT * NF * 2);
  size_t o_kb    = alloc((size_t)NB * NHEAD * TPAD * NDH * 2);
  size_t o_vb    = alloc((size_t)NB * NHEAD * NDH * TPAD2 * 2);
  size_t o_xnT   = alloc((size_t)NB * NHW * NC * 2);
  size_t o_attnT = alloc((size_t)NB * NHW * NC * 2);
  (void)ws_size; (void)in_sizes; (void)n_in; (void)out_size;

  float2* stats = (float2*)(ws + o_stats);
  USHORT* qwb = (USHORT*)(ws + o_qwb);
  USHORT* pwb = (USHORT*)(ws + o_pwb);
  USHORT* kwb = (USHORT*)(ws + o_kwb);
  USHORT* vwb = (USHORT*)(ws + o_vwb);
  USHORT* txb = (USHORT*)(ws + o_txb);
  USHORT* kbuf = (USHORT*)(ws + o_kb);
  USHORT* vbuf = (USHORT*)(ws + o_vb);
  USHORT* xnT = (USHORT*)(ws + o_xnT);
  USHORT* attnT = (USHORT*)(ws + o_attnT);

  const int n0 = (NC * NC) / 4, n1 = (NC * NC) / 4, n2 = (NC * NF) / 4, n3 = (NC * NF) / 4,
            n4 = (NB * NT * NF) / 4;
  const int ntot = n0 + n1 + n2 + n3 + n4;
  hipLaunchKernelGGL(cvt_all_kernel, dim3((ntot + 255) / 256), dim3(256), 0, stream,
                     q_w, qwb, n0, p_w, pwb, n1, k_w, kwb, n2, v_w, vwb, n3, text, txb, n4);

  hipLaunchKernelGGL(gnstats_kernel, dim3(512), dim3(256), 0, stream, x, stats);
  hipLaunchKernelGGL(gn_tr_kernel, dim3(512), dim3(1024), 0, stream, x, stats, gn_g, gn_b, xnT);
  hipLaunchKernelGGL(kvgemm_kernel, dim3(4, 2, 16), dim3(256), 0, stream, kwb, vwb, txb, k_b, v_b, kbuf, vbuf);
  hipLaunchKernelGGL(qattn_kernel, dim3(32, 4, 16), dim3(256), 0, stream, qwb, xnT, q_b, kbuf, vbuf, attnT);
  hipLaunchKernelGGL(projgemm_kernel, dim3(32, 4, 16), dim3(256), 0, stream, pwb, attnT, p_b, x, out);
}

// Round 18
// 241.127 us; speedup vs baseline: 1.2280x; 1.2280x over previous
//
#include <hip/hip_runtime.h>

typedef unsigned short USHORT;
typedef __attribute__((ext_vector_type(8))) short short8;
typedef __attribute__((ext_vector_type(4))) float f32x4;

#define NB   16
#define NC   512
#define NHW  4096
#define NT   77
#define NF   768
#define NHEAD 8
#define NDH  64
#define TPAD 80
#define TPAD2 96
#define PSTR 104   // P-tile LDS row stride in shorts: 208B == 20 mod 32 banks
#define BKS  64

__device__ __forceinline__ USHORT f2bf(float f){
  unsigned u = __builtin_bit_cast(unsigned, f);
  u += 0x7fffu + ((u >> 16) & 1u);
  return (USHORT)(u >> 16);
}
__device__ __forceinline__ unsigned pack2(float a, float b){
  return (unsigned)f2bf(a) | ((unsigned)f2bf(b) << 16);
}
__device__ __forceinline__ float bf2f(unsigned hs){
  return __builtin_bit_cast(float, hs << 16);
}

__device__ __forceinline__ void gload16(const void* g, void* l){
  __builtin_amdgcn_global_load_lds((const __attribute__((address_space(1))) unsigned*)g,
                                   (__attribute__((address_space(3))) unsigned*)l, 16, 0, 0);
}

// XCD-aware swizzle of a 32-wide tile index (T1).
__device__ __forceinline__ int xcd_swz32(int x){ return ((x & 7) << 2) | (x >> 3); }

// ---------------- single-launch f32 -> bf16 convert of all 5 arrays ----------------
__global__ __launch_bounds__(256) void cvt_all_kernel(const float* __restrict__ s0, USHORT* __restrict__ d0, int n0,
                                                      const float* __restrict__ s1, USHORT* __restrict__ d1, int n1,
                                                      const float* __restrict__ s2, USHORT* __restrict__ d2, int n2,
                                                      const float* __restrict__ s3, USHORT* __restrict__ d3, int n3,
                                                      const float* __restrict__ s4, USHORT* __restrict__ d4, int n4){
  int i = blockIdx.x * 256 + threadIdx.x;
  const float* s; USHORT* d;
  if (i < n0){ s = s0; d = d0; }
  else { i -= n0;
    if (i < n1){ s = s1; d = d1; }
    else { i -= n1;
      if (i < n2){ s = s2; d = d2; }
      else { i -= n2;
        if (i < n3){ s = s3; d = d3; }
        else { i -= n3;
          if (i >= n4) return;
          s = s4; d = d4; } } } }
  float4 v = ((const float4*)s)[i];
  uint2 pk; pk.x = pack2(v.x, v.y); pk.y = pack2(v.z, v.w);
  ((uint2*)d)[i] = pk;
}

// ---------------- FUSED GroupNorm via LDS tile (R14 BEST: total 242.3us) ----------------
// R11-R13: allocator refuses to keep a 64-float x-tile live across __syncthreads -> scratch.
// R15 (L2 re-read) and R16 (split w/ coalesced writes) both regressed. This version parks
// the tile in 128KB dynamic LDS as bf16 [16ch][4096s]; pass 1 packs+writes (uint2/thread/ch,
// lane stride 8B = conflict-free) while accumulating fp32 sum/sumsq; pass 2 reads back,
// normalizes in fp32, writes xnT. Registers ~45, WRITE 73MB clean.
__global__ __launch_bounds__(1024) void gn_fused_kernel(const float* __restrict__ x,
                                                        const float* __restrict__ gamma,
                                                        const float* __restrict__ beta,
                                                        USHORT* __restrict__ xnT){
  extern __shared__ USHORT tile[];          // [16][4096] bf16 = 128 KB dynamic
  __shared__ float red[34];
  const int dsp = blockIdx.x;
  const int o = (dsp >> 3) & 1;
  const int p = (dsp >> 4) * 8 + (dsp & 7);
  const int base = 2 * p + o;               // b*32 + g  (pairs g,g+1 land 8 apart -> same XCD)
  const int b = base >> 5, g = base & 31;
  const int t = threadIdx.x;                // 0..1023; owns s = t*4 .. t*4+3

  const float* xg = x + ((size_t)b * NC + g * 16) * NHW + t * 4;
  float s = 0.f, s2 = 0.f;
  #pragma unroll
  for (int c = 0; c < 16; c++){
    float4 v = *(const float4*)(xg + (size_t)c * NHW);
    s  += v.x + v.y + v.z + v.w;
    s2 += v.x*v.x + v.y*v.y + v.z*v.z + v.w*v.w;
    uint2 pk; pk.x = pack2(v.x, v.y); pk.y = pack2(v.z, v.w);
    *(uint2*)(tile + c * 4096 + t * 4) = pk;
  }

  #pragma unroll
  for (int off = 32; off; off >>= 1){ s += __shfl_down(s, off); s2 += __shfl_down(s2, off); }
  const int wv = t >> 6;
  if ((t & 63) == 0){ red[wv] = s; red[16 + wv] = s2; }
  __syncthreads();
  if (t == 0){
    float S = 0.f, S2 = 0.f;
    #pragma unroll
    for (int i = 0; i < 16; i++){ S += red[i]; S2 += red[16 + i]; }
    float mu = S * (1.0f / 65536.0f);
    float var = S2 * (1.0f / 65536.0f) - mu * mu;
    red[32] = mu;
    red[33] = 1.0f / sqrtf(var + 1e-5f);
  }
  __syncthreads();
  const float mu = red[32], rs = red[33];

  // block-uniform indices -> scalar loads (SGPRs)
  float ga[16], be[16];
  #pragma unroll
  for (int c = 0; c < 16; c++){ ga[c] = gamma[g * 16 + c] * rs; be[c] = beta[g * 16 + c]; }

  // read tile back: 16 named uint2 (short-lived, ~32 VGPR)
#define GN_RD(c) uint2 u##c = *(const uint2*)(tile + (c) * 4096 + t * 4);
  GN_RD(0)  GN_RD(1)  GN_RD(2)  GN_RD(3)  GN_RD(4)  GN_RD(5)  GN_RD(6)  GN_RD(7)
  GN_RD(8)  GN_RD(9)  GN_RD(10) GN_RD(11) GN_RD(12) GN_RD(13) GN_RD(14) GN_RD(15)
#undef GN_RD

  USHORT* ob = xnT + ((size_t)b * NHW + t * 4) * NC + g * 16;
  // e=0: low half of .x ; e=1: high half of .x ; e=2: low of .y ; e=3: high of .y
#define GN_VAL(c, W, HI) bf2f(HI ? (u##c.W >> 16) : (u##c.W & 0xffffu))
#define GN_STORE(W, HI, EIDX) { \
  unsigned w0 = pack2((GN_VAL(0,W,HI)  - mu) * ga[0]  + be[0],  (GN_VAL(1,W,HI)  - mu) * ga[1]  + be[1]);  \
  unsigned w1 = pack2((GN_VAL(2,W,HI)  - mu) * ga[2]  + be[2],  (GN_VAL(3,W,HI)  - mu) * ga[3]  + be[3]);  \
  unsigned w2 = pack2((GN_VAL(4,W,HI)  - mu) * ga[4]  + be[4],  (GN_VAL(5,W,HI)  - mu) * ga[5]  + be[5]);  \
  unsigned w3 = pack2((GN_VAL(6,W,HI)  - mu) * ga[6]  + be[6],  (GN_VAL(7,W,HI)  - mu) * ga[7]  + be[7]);  \
  unsigned w4 = pack2((GN_VAL(8,W,HI)  - mu) * ga[8]  + be[8],  (GN_VAL(9,W,HI)  - mu) * ga[9]  + be[9]);  \
  unsigned w5 = pack2((GN_VAL(10,W,HI) - mu) * ga[10] + be[10], (GN_VAL(11,W,HI) - mu) * ga[11] + be[11]); \
  unsigned w6 = pack2((GN_VAL(12,W,HI) - mu) * ga[12] + be[12], (GN_VAL(13,W,HI) - mu) * ga[13] + be[13]); \
  unsigned w7 = pack2((GN_VAL(14,W,HI) - mu) * ga[14] + be[14], (GN_VAL(15,W,HI) - mu) * ga[15] + be[15]); \
  uint4 p0{w0, w1, w2, w3}, p1{w4, w5, w6, w7};  \
  *(uint4*)(ob + (size_t)(EIDX) * NC) = p0;      \
  *(uint4*)(ob + (size_t)(EIDX) * NC + 8) = p1;  \
}
  GN_STORE(x, 0, 0) GN_STORE(x, 1, 1) GN_STORE(y, 0, 2) GN_STORE(y, 1, 3)
#undef GN_STORE
#undef GN_VAL
}

// ---------------- fallback: two-kernel GroupNorm (R6-proven) ----------------
__global__ __launch_bounds__(256) void gnstats_kernel(const float* __restrict__ x, float2* __restrict__ stats){
  int gid = blockIdx.x;
  const float4* p = (const float4*)(x + (size_t)gid * 65536);
  float s = 0.f, s2 = 0.f;
  for (int i = threadIdx.x; i < 16384; i += 256){
    float4 v = p[i];
    s  += v.x + v.y + v.z + v.w;
    s2 += v.x*v.x + v.y*v.y + v.z*v.z + v.w*v.w;
  }
  #pragma unroll
  for (int off = 32; off; off >>= 1){ s += __shfl_down(s, off); s2 += __shfl_down(s2, off); }
  __shared__ float red[8];
  int wv = threadIdx.x >> 6;
  if ((threadIdx.x & 63) == 0){ red[wv] = s; red[4 + wv] = s2; }
  __syncthreads();
  if (threadIdx.x == 0){
    float S  = red[0] + red[1] + red[2] + red[3];
    float S2 = red[4] + red[5] + red[6] + red[7];
    float mu = S * (1.0f / 65536.0f);
    float var = S2 * (1.0f / 65536.0f) - mu * mu;
    stats[gid] = make_float2(mu, 1.0f / sqrtf(var + 1e-5f));
  }
}

__global__ __launch_bounds__(256) void gnorm_tr_kernel(const float* __restrict__ x, const float2* __restrict__ stats,
                                                       const float* __restrict__ gamma, const float* __restrict__ beta,
                                                       USHORT* __restrict__ xnT){
  __shared__ float tile[64][65];
  int b = blockIdx.z, c0 = blockIdx.y * 64, s0 = blockIdx.x * 64;
  int col = threadIdx.x & 63;
  int row4 = threadIdx.x >> 6;
  const float* xp = x + ((size_t)b * NC + c0) * NHW + s0;
  #pragma unroll
  for (int i = 0; i < 16; i++){
    int r = i * 4 + row4;
    tile[r][col] = xp[(size_t)r * NHW + col];
  }
  __syncthreads();
  int c = c0 + col;
  int g = c >> 4;
  float2 st = stats[b * 32 + g];
  float ga = gamma[c], be = beta[c];
  USHORT* op = xnT + ((size_t)b * NHW + s0) * NC + c;
  #pragma unroll
  for (int i = 0; i < 16; i++){
    int s = i * 4 + row4;
    float v = (tile[col][s] - st.x) * st.y * ga + be;
    op[(size_t)s * NC] = f2bf(v);
  }
}

// ---------------- 128x128-tile single-buffer LDS GEMM core (R2/R6 proven) ----------------
// Frozen: min-waves>=4 (R5/R7), dbuf (R3), 256^2-2phase (R9), LDS-transpose epilogue (R10)
// all measured null/regressions vs this structure.
__device__ __forceinline__ void gemm128_core(const USHORT* __restrict__ A, const USHORT* __restrict__ B,
                                             int m0, size_t brow0, USHORT* Alds, USHORT* Blds,
                                             f32x4 (&acc)[4][4]){
  const int tid = threadIdx.x;
  const int lane = tid & 63, wave = tid >> 6;
  const int l15 = lane & 15, lg = lane >> 4;
  const int wm = wave >> 1, wn = wave & 1;
  const int srow = lane >> 3, sslot = lane & 7;

  #pragma unroll
  for (int i = 0; i < 4; i++)
    #pragma unroll
    for (int j = 0; j < 4; j++) acc[i][j] = f32x4{0.f, 0.f, 0.f, 0.f};

  for (int k0 = 0; k0 < 512; k0 += BKS){
    #pragma unroll
    for (int i = 0; i < 4; i++){
      const int r0 = wave * 32 + i * 8;
      const int row = r0 + srow;
      const int slot = sslot ^ (row & 7);
      gload16(A + (size_t)(m0 + row) * NC + k0 + slot * 8, Alds + r0 * BKS);
      gload16(B + brow0 + (size_t)row * NC + k0 + slot * 8, Blds + r0 * BKS);
    }
    __syncthreads();
    #pragma unroll
    for (int ks = 0; ks < 2; ks++){
      short8 af[4], bf[4];
      #pragma unroll
      for (int i = 0; i < 4; i++){
        const int row = wm * 64 + i * 16 + l15;
        af[i] = *(const short8*)(Alds + row * BKS + (((ks * 4 + lg) ^ (row & 7)) * 8));
      }
      #pragma unroll
      for (int j = 0; j < 4; j++){
        const int row = wn * 64 + j * 16 + l15;
        bf[j] = *(const short8*)(Blds + row * BKS + (((ks * 4 + lg) ^ (row & 7)) * 8));
      }
      #pragma unroll
      for (int i = 0; i < 4; i++)
        #pragma unroll
        for (int j = 0; j < 4; j++)
          acc[i][j] = __builtin_amdgcn_mfma_f32_16x16x32_bf16(af[i], bf[j], acc[i][j], 0, 0, 0);
    }
    __syncthreads();
  }
}

// ---------------- FUSED Q-GEMM + attention (R8 proven, unchanged) ----------------
__global__ __launch_bounds__(256, 3) void qattn_kernel(const USHORT* __restrict__ Aw, const USHORT* __restrict__ Bx,
                                                       const float* __restrict__ bias,
                                                       const USHORT* __restrict__ kb, const USHORT* __restrict__ vb,
                                                       USHORT* __restrict__ attnT){
  __shared__ USHORT smem[26624];   // 52 KB
  const int lane = threadIdx.x & 63, wave = threadIdx.x >> 6;
  const int l15 = lane & 15, lg = lane >> 4;
  const int b = blockIdx.z;
  const int xx = xcd_swz32(blockIdx.x);
  const int m0b = blockIdx.y * 128;
  const size_t brow0 = ((size_t)b * NHW + xx * 128) * NC;
  f32x4 acc[4][4];
  gemm128_core(Aw, Bx, m0b, brow0, smem, smem + 8192, acc);

  const int wm = wave >> 1, wn = wave & 1;
  const int h = blockIdx.y * 2 + wm;
  const int m0 = h * 64;
  const int s0 = xx * 128 + wn * 64;
  const size_t bh = (size_t)b * NHEAD + h;
  char* qt = (char*)(smem + wave * 6656);     // 13 KB wave-private region

  #pragma unroll
  for (int i = 0; i < 4; i++){
    const int dbase = i * 16 + lg * 4;
    float b0 = bias[m0 + dbase], b1 = bias[m0 + dbase + 1];
    float b2 = bias[m0 + dbase + 2], b3 = bias[m0 + dbase + 3];
    #pragma unroll
    for (int j = 0; j < 4; j++){
      const int s = j * 16 + l15;
      uint2 pk;
      pk.x = pack2(acc[i][j][0] + b0, acc[i][j][1] + b1);
      pk.y = pack2(acc[i][j][2] + b2, acc[i][j][3] + b3);
      *(uint2*)(qt + s * 128 + ((dbase * 2) ^ ((s & 7) << 4))) = pk;
    }
  }
  short8 aq[4][2];
  #pragma unroll
  for (int i = 0; i < 4; i++){
    const int s = i * 16 + l15;
    #pragma unroll
    for (int ks = 0; ks < 2; ks++)
      aq[i][ks] = *(const short8*)(qt + s * 128 + ((ks * 64 + lg * 16) ^ ((s & 7) << 4)));
  }

  USHORT* plds = (USHORT*)qt;
  uint4 z{0u, 0u, 0u, 0u};
  *(uint4*)(qt + lane * (PSTR * 2) + 160) = z;
  *(uint4*)(qt + lane * (PSTR * 2) + 176) = z;

  short8 bk[5][2];
  const USHORT* kp = kb + bh * TPAD * NDH;
  #pragma unroll
  for (int j = 0; j < 5; j++)
    #pragma unroll
    for (int ks = 0; ks < 2; ks++)
      bk[j][ks] = *(const short8*)(kp + (j * 16 + l15) * NDH + ks * 32 + lg * 8);

  f32x4 sacc[4][5];
  #pragma unroll
  for (int i = 0; i < 4; i++)
    #pragma unroll
    for (int j = 0; j < 5; j++) sacc[i][j] = f32x4{0.f, 0.f, 0.f, 0.f};
  #pragma unroll
  for (int ks = 0; ks < 2; ks++)
    #pragma unroll
    for (int i = 0; i < 4; i++)
      #pragma unroll
      for (int j = 0; j < 5; j++)
        sacc[i][j] = __builtin_amdgcn_mfma_f32_16x16x32_bf16(aq[i][ks], bk[j][ks], sacc[i][j], 0, 0, 0);

  const float scale = 0.125f;
  #pragma unroll
  for (int i = 0; i < 4; i++){
    float v[5][4], mx[4], sm[4];
    #pragma unroll
    for (int r = 0; r < 4; r++) mx[r] = -3.0e38f;
    #pragma unroll
    for (int j = 0; j < 5; j++)
      #pragma unroll
      for (int r = 0; r < 4; r++){
        float t = sacc[i][j][r] * scale;
        if (j == 4 && l15 >= 13) t = -3.0e38f;
        v[j][r] = t;
        mx[r] = fmaxf(mx[r], t);
      }
    #pragma unroll
    for (int r = 0; r < 4; r++)
      #pragma unroll
      for (int d = 1; d < 16; d <<= 1) mx[r] = fmaxf(mx[r], __shfl_xor(mx[r], d));
    #pragma unroll
    for (int r = 0; r < 4; r++) sm[r] = 0.f;
    #pragma unroll
    for (int j = 0; j < 5; j++)
      #pragma unroll
      for (int r = 0; r < 4; r++){
        float p = __expf(v[j][r] - mx[r]);
        v[j][r] = p;
        sm[r] += p;
      }
    #pragma unroll
    for (int r = 0; r < 4; r++)
      #pragma unroll
      for (int d = 1; d < 16; d <<= 1) sm[r] += __shfl_xor(sm[r], d);
    #pragma unroll
    for (int r = 0; r < 4; r++){
      float inv = 1.0f / sm[r];
      #pragma unroll
      for (int j = 0; j < 5; j++)
        plds[(i * 16 + lg * 4 + r) * PSTR + j * 16 + l15] = f2bf(v[j][r] * inv);
    }
  }

  f32x4 oacc[4][4];
  #pragma unroll
  for (int it = 0; it < 4; it++)
    #pragma unroll
    for (int jt = 0; jt < 4; jt++) oacc[it][jt] = f32x4{0.f, 0.f, 0.f, 0.f};
  const USHORT* vp = vb + bh * NDH * TPAD2;
  #pragma unroll
  for (int ks = 0; ks < 3; ks++){
    short8 av[4], bpv[4];
    #pragma unroll
    for (int it = 0; it < 4; it++)
      av[it] = *(const short8*)(vp + (it * 16 + l15) * TPAD2 + ks * 32 + lg * 8);
    #pragma unroll
    for (int jt = 0; jt < 4; jt++)
      bpv[jt] = *(const short8*)(plds + (jt * 16 + l15) * PSTR + ks * 32 + lg * 8);
    #pragma unroll
    for (int it = 0; it < 4; it++)
      #pragma unroll
      for (int jt = 0; jt < 4; jt++)
        oacc[it][jt] = __builtin_amdgcn_mfma_f32_16x16x32_bf16(av[it], bpv[jt], oacc[it][jt], 0, 0, 0);
  }

  USHORT* ob = attnT + ((size_t)b * NHW + s0) * NC + h * NDH;
  #pragma unroll
  for (int it = 0; it < 4; it++)
    #pragma unroll
    for (int jt = 0; jt < 4; jt++){
      const int sl = jt * 16 + l15;
      uint2 pk;
      pk.x = pack2(oacc[it][jt][0], oacc[it][jt][1]);
      pk.y = pack2(oacc[it][jt][2], oacc[it][jt][3]);
      *(uint2*)(ob + (size_t)sl * NC + it * 16 + lg * 4) = pk;
    }
}

// ---------------- proj GEMM + bias + residual -> out fp32 [b][c][hw] (R6/R8 proven) ----------------
__global__ __launch_bounds__(256, 3) void projgemm_kernel(const USHORT* __restrict__ Aw, const USHORT* __restrict__ Battn,
                                                          const float* __restrict__ bias, const float* __restrict__ xres,
                                                          float* __restrict__ out){
  __shared__ USHORT Alds[128 * BKS], Blds[128 * BKS];
  const int b = blockIdx.z;
  const int xx = xcd_swz32(blockIdx.x);
  const int m0b = blockIdx.y * 128;
  const size_t brow0 = ((size_t)b * NHW + xx * 128) * NC;
  f32x4 acc[4][4];
  gemm128_core(Aw, Battn, m0b, brow0, Alds, Blds, acc);

  const int lane = threadIdx.x & 63, wave = threadIdx.x >> 6;
  const int l15 = lane & 15, lg = lane >> 4;
  const int m0 = m0b + (wave >> 1) * 64;
  const int n0 = xx * 128 + (wave & 1) * 64;
  #pragma unroll
  for (int i = 0; i < 4; i++){
    const int ob = m0 + i * 16 + lg * 4;
    #pragma unroll
    for (int r = 0; r < 4; r++){
      const int oc = ob + r;
      const float bb = bias[oc];
      #pragma unroll
      for (int j = 0; j < 4; j++){
        const int s = n0 + j * 16 + l15;
        const size_t idx = ((size_t)b * NC + oc) * NHW + s;
        out[idx] = acc[i][j][r] + bb + xres[idx];
      }
    }
  }
}

// ---------------- small-K MFMA core for the 77-token projections ----------------
template<int KLEN>
__device__ __forceinline__ void mfma_core(const USHORT* const (&ap)[4], const USHORT* const (&bp)[4],
                                          f32x4 (&acc)[4][4]){
  short8 a_c[4], b_c[4];
  #pragma unroll
  for (int i = 0; i < 4; i++){ a_c[i] = *(const short8*)ap[i]; b_c[i] = *(const short8*)bp[i]; }
  #pragma unroll 2
  for (int k0 = 0; k0 < KLEN; k0 += 32){
    short8 a_n[4], b_n[4];
    if (k0 + 32 < KLEN){
      #pragma unroll
      for (int i = 0; i < 4; i++){
        a_n[i] = *(const short8*)(ap[i] + k0 + 32);
        b_n[i] = *(const short8*)(bp[i] + k0 + 32);
      }
    }
    #pragma unroll
    for (int i = 0; i < 4; i++)
      #pragma unroll
      for (int j = 0; j < 4; j++)
        acc[i][j] = __builtin_amdgcn_mfma_f32_16x16x32_bf16(a_c[i], b_c[j], acc[i][j], 0, 0, 0);
    #pragma unroll
    for (int i = 0; i < 4; i++){ a_c[i] = a_n[i]; b_c[i] = b_n[i]; }
  }
}

// ---------------- K+V GEMM (single launch, mode = blockIdx.y) + raw-reshape scatter ----------------
__global__ __launch_bounds__(256, 2) void kvgemm_kernel(const USHORT* __restrict__ kw, const USHORT* __restrict__ vw,
                                                        const USHORT* __restrict__ Tx,
                                                        const float* __restrict__ kbias, const float* __restrict__ vbias,
                                                        USHORT* __restrict__ kdst, USHORT* __restrict__ vdst){
  const int lane = threadIdx.x & 63, wave = threadIdx.x >> 6;
  const int l15 = lane & 15, lg = lane >> 4;
  const int b = blockIdx.z;
  const int mode = blockIdx.y;
  const USHORT* Wt = mode ? vw : kw;
  const float* bias = mode ? vbias : kbias;
  USHORT* dst = mode ? vdst : kdst;
  const int m0 = (wave >> 1) * 64;
  const int n0 = blockIdx.x * 128 + (wave & 1) * 64;
  const USHORT* ap[4]; const USHORT* bp[4];
  #pragma unroll
  for (int i = 0; i < 4; i++){
    int r = m0 + i * 16 + l15; r = r > 76 ? 76 : r;
    ap[i] = Tx + ((size_t)b * NT + r) * NF + lg * 8;
  }
  #pragma unroll
  for (int i = 0; i < 4; i++) bp[i] = Wt + (size_t)(n0 + i * 16 + l15) * NF + lg * 8;
  f32x4 acc[4][4];
  #pragma unroll
  for (int i = 0; i < 4; i++)
    #pragma unroll
    for (int j = 0; j < 4; j++) acc[i][j] = f32x4{0.f, 0.f, 0.f, 0.f};
  mfma_core<NF>(ap, bp, acc);
  #pragma unroll
  for (int i = 0; i < 4; i++){
    const int tb = m0 + i * 16 + lg * 4;
    #pragma unroll
    for (int r = 0; r < 4; r++){
      const int t = tb + r;
      if (t < NT){
        #pragma unroll
        for (int j = 0; j < 4; j++){
          const int c = n0 + j * 16 + l15;
          float v = acc[i][j][r] + bias[c];
          int fi = t * NC + c;
          int hh = fi / 4928;
          int rem = fi - hh * 4928;
          int dd = rem / 77;
          int tt = rem - dd * 77;
          size_t bhh = (size_t)(b * NHEAD + hh);
          if (mode == 0) dst[(bhh * TPAD + tt) * NDH + dd] = f2bf(v);
          else           dst[(bhh * NDH + dd) * TPAD2 + tt] = f2bf(v);
        }
      }
    }
  }
}

extern "C" void kernel_launch(void* const* d_in, const int* in_sizes, int n_in,
                              void* d_out, int out_size, void* d_ws, size_t ws_size,
                              hipStream_t stream){
  const float* x    = (const float*)d_in[0];
  const float* text = (const float*)d_in[1];
  const float* gn_g = (const float*)d_in[2];
  const float* gn_b = (const float*)d_in[3];
  const float* q_w  = (const float*)d_in[4];
  const float* q_b  = (const float*)d_in[5];
  const float* k_w  = (const float*)d_in[6];
  const float* k_b  = (const float*)d_in[7];
  const float* v_w  = (const float*)d_in[8];
  const float* v_b  = (const float*)d_in[9];
  const float* p_w  = (const float*)d_in[10];
  const float* p_b  = (const float*)d_in[11];
  float* out = (float*)d_out;

  char* ws = (char*)d_ws;
  size_t off = 0;
  auto alloc = [&](size_t bytes){ size_t o = off; off = (off + bytes + 255) & ~(size_t)255; return o; };
  size_t o_stats = alloc(512 * 8);
  size_t o_qwb   = alloc((size_t)NC * NC * 2);
  size_t o_pwb   = alloc((size_t)NC * NC * 2);
  size_t o_kwb   = alloc((size_t)NC * NF * 2);
  size_t o_vwb   = alloc((size_t)NC * NF * 2);
  size_t o_txb   = alloc((size_t)NB * NT * NF * 2);
  size_t o_kb    = alloc((size_t)NB * NHEAD * TPAD * NDH * 2);
  size_t o_vb    = alloc((size_t)NB * NHEAD * NDH * TPAD2 * 2);
  size_t o_xnT   = alloc((size_t)NB * NHW * NC * 2);
  size_t o_attnT = alloc((size_t)NB * NHW * NC * 2);
  (void)ws_size; (void)in_sizes; (void)n_in; (void)out_size;

  float2* stats = (float2*)(ws + o_stats);
  USHORT* qwb = (USHORT*)(ws + o_qwb);
  USHORT* pwb = (USHORT*)(ws + o_pwb);
  USHORT* kwb = (USHORT*)(ws + o_kwb);
  USHORT* vwb = (USHORT*)(ws + o_vwb);
  USHORT* txb = (USHORT*)(ws + o_txb);
  USHORT* kbuf = (USHORT*)(ws + o_kb);
  USHORT* vbuf = (USHORT*)(ws + o_vb);
  USHORT* xnT = (USHORT*)(ws + o_xnT);
  USHORT* attnT = (USHORT*)(ws + o_attnT);

  const int n0 = (NC * NC) / 4, n1 = (NC * NC) / 4, n2 = (NC * NF) / 4, n3 = (NC * NF) / 4,
            n4 = (NB * NT * NF) / 4;
  const int ntot = n0 + n1 + n2 + n3 + n4;
  hipLaunchKernelGGL(cvt_all_kernel, dim3((ntot + 255) / 256), dim3(256), 0, stream,
                     q_w, qwb, n0, p_w, pwb, n1, k_w, kwb, n2, v_w, vwb, n3, text, txb, n4);

  // fused GN needs 128 KB dynamic LDS (host-side attribute set; graph-capture safe, R9-proven).
  hipError_t e = hipFuncSetAttribute((const void*)gn_fused_kernel,
                                     hipFuncAttributeMaxDynamicSharedMemorySize, 131072);
  if (e == hipSuccess){
    hipLaunchKernelGGL(gn_fused_kernel, dim3(512), dim3(1024), 131072, stream, x, gn_g, gn_b, xnT);
  } else {
    hipLaunchKernelGGL(gnstats_kernel, dim3(512), dim3(256), 0, stream, x, stats);
    hipLaunchKernelGGL(gnorm_tr_kernel, dim3(64, 8, 16), dim3(256), 0, stream, x, stats, gn_g, gn_b, xnT);
  }
  hipLaunchKernelGGL(kvgemm_kernel, dim3(4, 2, 16), dim3(256), 0, stream, kwb, vwb, txb, k_b, v_b, kbuf, vbuf);
  hipLaunchKernelGGL(qattn_kernel, dim3(32, 4, 16), dim3(256), 0, stream, qwb, xnT, q_b, kbuf, vbuf, attnT);
  hipLaunchKernelGGL(projgemm_kernel, dim3(32, 4, 16), dim3(256), 0, stream, pwb, attnT, p_b, x, out);
}